// Round 8
// baseline (679.042 us; speedup 1.0000x reference)
//
#include <hip/hip_runtime.h>
#include <hip/hip_bf16.h>
#include <stdint.h>

// GraRPINet: 2-layer GAT. N=40000 nodes, E=640000 edges.
// R3: all GEMMs -> bf16 MFMA (16x16x32), weights pre-transposed bf16 BT[n][k].
// R4/R6/R7 (reverted): LDS-free embed, global split-K partials, BM=32 all regressed.
// Lesson: zero extra DRAM-visible traffic; embed is GRID-starved (625 rna blocks
// = 2.44/CU x 4 waves = 30% occupancy).
// R8 (WIN, 762->707): attn_proj folded into layer_gemm; edge_softmax fused into agg.
// R9 (neutral): layer_gemm col-group G=2. R10 (WIN, 701->655): online-softmax
// single-pass gat_fused + VEC=8 gathers.
// R11: embed split-K INSIDE the block: 512 threads, wave-group g handles K-half g
// in its own LDS tiles, LDS fp32 reduce at the end. Same blocks, same global access
// pattern, zero extra traffic -- just 2x waves/block for the grid-starved tail.

#define HEADS 4
#define CH1   64
#define CH2   32
#define HC1   256
#define HC2   128

static constexpr int D_RNA  = 1000;
static constexpr int D_PROT = 300;
static constexpr int D_IN   = 1300;
static constexpr int HDIM   = 128;  // 2H

typedef __bf16 bf16x8 __attribute__((ext_vector_type(8)));
typedef float  f32x4  __attribute__((ext_vector_type(4)));
typedef unsigned short ushort;

__device__ __forceinline__ float lrelu(float x) { return x >= 0.f ? x : 0.2f * x; }
__device__ __forceinline__ float bf2f(unsigned int u16) {
  return __uint_as_float(u16 << 16);
}
__device__ __forceinline__ ushort f2bf(float f) {
  union { float f; unsigned int u; } x; x.f = f;
  unsigned int r = x.u + 0x7fffu + ((x.u >> 16) & 1u);
  return (ushort)(r >> 16);
}

// ---------------- small utility kernels ----------------
__global__ void zero_i32(int* p, int n) {
  int i = blockIdx.x * 256 + threadIdx.x;
  if (i < n) p[i] = 0;
}

__global__ void hist_kernel(const int* __restrict__ dstv, int* __restrict__ deg, int E) {
  int i = blockIdx.x * 256 + threadIdx.x;
  if (i < E) atomicAdd(&deg[dstv[i]], 1);
}

__global__ void scan_kernel(const int* __restrict__ deg, int* __restrict__ off,
                            int* __restrict__ cur, int n) {
  __shared__ int s[1024];
  int tid = threadIdx.x;
  const int CHK = (n + 1023) / 1024;
  int base = tid * CHK;
  int sum = 0;
  for (int j = 0; j < CHK; ++j) {
    int i = base + j;
    if (i < n) sum += deg[i];
  }
  s[tid] = sum;
  __syncthreads();
  for (int o = 1; o < 1024; o <<= 1) {
    int t = (tid >= o) ? s[tid - o] : 0;
    __syncthreads();
    s[tid] += t;
    __syncthreads();
  }
  int run = s[tid] - sum;
  for (int j = 0; j < CHK; ++j) {
    int i = base + j;
    if (i < n) {
      off[i] = run; cur[i] = run;
      run += deg[i];
    }
  }
  if (tid == 1023) off[n] = s[1023];
}

__global__ void scatter_kernel(const int* __restrict__ srcv, const int* __restrict__ dstv,
                               int* __restrict__ cur, int* __restrict__ srcs, int E) {
  int i = blockIdx.x * 256 + threadIdx.x;
  if (i < E) {
    int d = dstv[i];
    int pos = atomicAdd(&cur[d], 1);
    srcs[pos] = srcv[i];
  }
}

// fold att vectors v[k,h] = sum_c W[k, h*CH+c]*att[h,c], then pack as GEMM B-tiles:
// BTA[64][K]: rows 0..3 = vs_hi, 4..7 = vs_lo, 8..11 = vd_hi, 12..15 = vd_lo,
// rows 16..63 = 0. hi/lo bf16 split keeps logits at ~fp32 precision.
__global__ void fold_att_kernel(const float* __restrict__ W1s, const float* __restrict__ W1d,
                                const float* __restrict__ at1s, const float* __restrict__ at1d,
                                const float* __restrict__ W2s, const float* __restrict__ W2d,
                                const float* __restrict__ at2s, const float* __restrict__ at2d,
                                ushort* __restrict__ BTA1, ushort* __restrict__ BTA2) {
  int tid = blockIdx.x * blockDim.x + threadIdx.x;
  int stride = gridDim.x * blockDim.x;
  for (int o = tid; o < HDIM * HEADS; o += stride) {
    int k = o >> 2, h = o & 3;
    float ss = 0.f, sd = 0.f;
    for (int c = 0; c < CH1; ++c) {
      ss += W1s[k * HC1 + h * CH1 + c] * at1s[h * CH1 + c];
      sd += W1d[k * HC1 + h * CH1 + c] * at1d[h * CH1 + c];
    }
    ushort sh = f2bf(ss), dh = f2bf(sd);
    BTA1[(0 + h) * HDIM + k] = sh;
    BTA1[(4 + h) * HDIM + k] = f2bf(ss - bf2f(sh));
    BTA1[(8 + h) * HDIM + k] = dh;
    BTA1[(12 + h) * HDIM + k] = f2bf(sd - bf2f(dh));
  }
  for (int o = tid; o < HC1 * HEADS; o += stride) {
    int k = o >> 2, h = o & 3;
    float ss = 0.f, sd = 0.f;
    for (int c = 0; c < CH2; ++c) {
      ss += W2s[k * HC2 + h * CH2 + c] * at2s[h * CH2 + c];
      sd += W2d[k * HC2 + h * CH2 + c] * at2d[h * CH2 + c];
    }
    ushort sh = f2bf(ss), dh = f2bf(sd);
    BTA2[(0 + h) * HC1 + k] = sh;
    BTA2[(4 + h) * HC1 + k] = f2bf(ss - bf2f(sh));
    BTA2[(8 + h) * HC1 + k] = dh;
    BTA2[(12 + h) * HC1 + k] = f2bf(sd - bf2f(dh));
  }
  for (int i = tid; i < 48 * HDIM; i += stride) BTA1[16 * HDIM + i] = 0;
  for (int i = tid; i < 48 * HC1; i += stride) BTA2[16 * HC1 + i] = 0;
}

// ---------------- weight preprocessing: transpose + bf16 ----------------
// BTr[64][1024] (k>=1000 zero), BTp[64][384] (k>=300 zero),
// BT1[512][128] = [W1s|Wl1]^T, BT2[256][256] = [W2s|Wl2]^T, concat biases.
__global__ void convert_weights(const float* __restrict__ W_rna, const float* __restrict__ W_prot,
                                const float* __restrict__ W1s, const float* __restrict__ Wl1,
                                const float* __restrict__ W2s, const float* __restrict__ Wl2,
                                const float* __restrict__ b1, const float* __restrict__ bl1,
                                const float* __restrict__ b2, const float* __restrict__ bl2,
                                ushort* BTr, ushort* BTp, ushort* BT1, ushort* BT2,
                                float* biasL1, float* biasL2) {
  int tid = blockIdx.x * blockDim.x + threadIdx.x;
  int stride = gridDim.x * blockDim.x;
  for (int i = tid; i < 64 * 1024; i += stride) {
    int n = i >> 10, k = i & 1023;
    BTr[i] = (k < D_RNA) ? f2bf(W_rna[k * 64 + n]) : 0;
  }
  for (int i = tid; i < 64 * 384; i += stride) {
    int n = i / 384, k = i - n * 384;
    BTp[i] = (k < D_PROT) ? f2bf(W_prot[k * 64 + n]) : 0;
  }
  for (int i = tid; i < 512 * 128; i += stride) {
    int n = i >> 7, k = i & 127;
    BT1[i] = f2bf(n < 256 ? W1s[k * 256 + n] : Wl1[k * 256 + n - 256]);
  }
  for (int i = tid; i < 256 * 256; i += stride) {
    int n = i >> 8, k = i & 255;
    BT2[i] = f2bf(n < 128 ? W2s[k * 128 + n] : Wl2[k * 128 + n - 128]);
  }
  for (int i = tid; i < 512; i += stride) biasL1[i] = (i < 256) ? b1[i] : bl1[i - 256];
  for (int i = tid; i < 256; i += stride) biasL2[i] = (i < 128) ? b2[i] : bl2[i - 128];
}

#define LDK 72  // padded k-stride (shorts) for 64-wide k tiles: 144B rows -> 2-way-only conflicts

__device__ __forceinline__ f32x4 mfma_bf16(bf16x8 a, bf16x8 b, f32x4 c) {
  return __builtin_amdgcn_mfma_f32_16x16x32_bf16(a, b, c, 0, 0, 0);
}

// ---------------- embedding MFMA GEMM: h0[N,128] bf16, in-block split-K ----------
// grid (2, N/64), 512 threads (8 waves). Wave-group g = K-half g, own LDS tiles,
// lockstep iteration counts (rna 8/8, prot 3/3 via BTp Kpad=384). Epilogue: group 1
// dumps fp32 acc to LDS (aliases dead staging buffers), group 0 adds + writes h0.
// Global access pattern identical to the R5 256-thread version; 2x waves/block.
__launch_bounds__(512)
__global__ void embed_gemm(const float* __restrict__ x,
                           const ushort* __restrict__ BTr, const ushort* __restrict__ BTp,
                           const float* __restrict__ b_rna, const float* __restrict__ b_prot,
                           ushort* __restrict__ h0) {
  const bool prot = (blockIdx.x == 1);
  const int Kpad  = prot ? 384 : 1024;
  const int Khalf = Kpad >> 1;           // 192 / 512
  const int iters = Khalf >> 6;          // 3 / 8
  const int acol  = prot ? D_RNA : 0;
  const ushort* BT = prot ? BTp : BTr;
  const float* bias = prot ? b_prot : b_rna;
  const int r0 = blockIdx.y * 64;

  __shared__ ushort As[2][64 * LDK];
  __shared__ ushort Bs[2][64 * LDK];
  int tid = threadIdx.x;                 // 0..511
  int g = tid >> 8;                      // K-half group
  int t = tid & 255;
  int wave = t >> 6, lane = tid & 63;
  int quad = lane >> 4, lr = lane & 15;
  const int kbase = g * Khalf;

  f32x4 acc[4];
#pragma unroll
  for (int c = 0; c < 4; ++c) acc[c] = (f32x4){0.f, 0.f, 0.f, 0.f};

  int srow = t >> 2, skq = (t & 3) * 16;
  const float* aprow = x + (size_t)(r0 + srow) * D_IN;
  const ushort* bprow = BT + (size_t)srow * Kpad + kbase;

  float4 fa[4];
  uint4 fb0, fb1;

  auto loadA = [&](int k0) {
#pragma unroll
    for (int q = 0; q < 4; ++q) {
      int col = acol + kbase + k0 + skq + q * 4;
      fa[q] = (col + 4 <= D_IN) ? *(const float4*)(aprow + col)
                                : make_float4(0.f, 0.f, 0.f, 0.f);
    }
  };
  auto loadB = [&](int k0) {
    const ushort* bp = bprow + k0 + skq;
    fb0 = *(const uint4*)bp;
    fb1 = *(const uint4*)(bp + 8);
  };

  loadA(0);
  loadB(0);

  for (int it = 0; it < iters; ++it) {
    {
      ushort tmp[16];
#pragma unroll
      for (int q = 0; q < 4; ++q) {
        tmp[q * 4 + 0] = f2bf(fa[q].x); tmp[q * 4 + 1] = f2bf(fa[q].y);
        tmp[q * 4 + 2] = f2bf(fa[q].z); tmp[q * 4 + 3] = f2bf(fa[q].w);
      }
      *(uint4*)&As[g][srow * LDK + skq] = *(const uint4*)&tmp[0];
      *(uint4*)&As[g][srow * LDK + skq + 8] = *(const uint4*)&tmp[8];
      *(uint4*)&Bs[g][srow * LDK + skq] = fb0;
      *(uint4*)&Bs[g][srow * LDK + skq + 8] = fb1;
    }
    __syncthreads();
    if (it + 1 < iters) {
      loadA((it + 1) * 64);
      loadB((it + 1) * 64);
    }
    int arow = wave * 16 + lr;
    bf16x8 a0 = *(const bf16x8*)&As[g][arow * LDK + quad * 8];
    bf16x8 a1 = *(const bf16x8*)&As[g][arow * LDK + 32 + quad * 8];
#pragma unroll
    for (int c = 0; c < 4; ++c) {
      bf16x8 b0 = *(const bf16x8*)&Bs[g][(c * 16 + lr) * LDK + quad * 8];
      bf16x8 b1 = *(const bf16x8*)&Bs[g][(c * 16 + lr) * LDK + 32 + quad * 8];
      acc[c] = mfma_bf16(a0, b0, acc[c]);
      acc[c] = mfma_bf16(a1, b1, acc[c]);
    }
    __syncthreads();
  }

  // in-block split-K reduce: red[64][65] fp32 aliases the dead staging LDS
  float* red = (float*)&As[0][0];   // 64*65*4 = 16640B <= 18432B (As total)
  if (g == 1) {
#pragma unroll
    for (int c = 0; c < 4; ++c) {
#pragma unroll
      for (int j = 0; j < 4; ++j) {
        int row_l = wave * 16 + quad * 4 + j;
        red[row_l * 65 + c * 16 + lr] = acc[c][j];
      }
    }
  }
  __syncthreads();
  if (g == 0) {
    int colb = prot ? 64 : 0;
#pragma unroll
    for (int c = 0; c < 4; ++c) {
#pragma unroll
      for (int j = 0; j < 4; ++j) {
        int row_l = wave * 16 + quad * 4 + j;
        int col = c * 16 + lr;
        float v = acc[c][j] + red[row_l * 65 + col] + bias[col];
        h0[(size_t)(r0 + row_l) * HDIM + colb + col] = f2bf(v);
      }
    }
  }
}

// ---------------- layer MFMA GEMM (col-group G=2) + folded attention logits ----------
// grid (ngroups+1, N/64). Regular block x: cols [x*128, x*128+128) = 2 B-tiles sharing
// one staged A-tile. Last x-block uses BTA (single tile) and writes fp32 a_s/a_d:
// out col t(0..3) hi + col t+4 lo summed via shfl_xor(4) -> a_s; cols 8..15 -> a_d.
__launch_bounds__(256)
__global__ void layer_gemm(const ushort* __restrict__ A, int K,
                           const ushort* __restrict__ BT, const float* __restrict__ bias,
                           ushort* __restrict__ out0, ushort* __restrict__ out1, int halfw,
                           const ushort* __restrict__ BTA,
                           float* __restrict__ a_s, float* __restrict__ a_d) {
  const bool att = (blockIdx.x == gridDim.x - 1);
  const int cb = att ? 0 : blockIdx.x * 128;
  const int r0 = blockIdx.y * 64;
  __shared__ ushort As[64 * LDK];
  __shared__ ushort Bs[2][64 * LDK];
  int tid = threadIdx.x;
  int wave = tid >> 6, lane = tid & 63;
  int quad = lane >> 4, lr = lane & 15;
  f32x4 acc[8];
#pragma unroll
  for (int c = 0; c < 8; ++c) acc[c] = (f32x4){0.f, 0.f, 0.f, 0.f};

  int srow = tid >> 2, skq = (tid & 3) * 16;
  const ushort* aprow = A + (size_t)(r0 + srow) * K;
  const ushort* bprow0 = att ? (BTA + (size_t)srow * K)
                             : (BT + (size_t)(cb + srow) * K);
  const ushort* bprow1 = BT + (size_t)(cb + 64 + srow) * K;   // unused when att

  uint4 fa0, fa1, fb00, fb01, fb10, fb11;
  auto loadAB = [&](int k0) {
    const ushort* ap = aprow + k0 + skq;
    fa0 = *(const uint4*)ap;
    fa1 = *(const uint4*)(ap + 8);
    const ushort* bp0 = bprow0 + k0 + skq;
    fb00 = *(const uint4*)bp0;
    fb01 = *(const uint4*)(bp0 + 8);
    if (!att) {
      const ushort* bp1 = bprow1 + k0 + skq;
      fb10 = *(const uint4*)bp1;
      fb11 = *(const uint4*)(bp1 + 8);
    }
  };

  loadAB(0);

  for (int k0 = 0; k0 < K; k0 += 64) {
    *(uint4*)&As[srow * LDK + skq] = fa0;
    *(uint4*)&As[srow * LDK + skq + 8] = fa1;
    *(uint4*)&Bs[0][srow * LDK + skq] = fb00;
    *(uint4*)&Bs[0][srow * LDK + skq + 8] = fb01;
    if (!att) {
      *(uint4*)&Bs[1][srow * LDK + skq] = fb10;
      *(uint4*)&Bs[1][srow * LDK + skq + 8] = fb11;
    }
    __syncthreads();
    if (k0 + 64 < K) loadAB(k0 + 64);
    int arow = wave * 16 + lr;
    bf16x8 a0 = *(const bf16x8*)&As[arow * LDK + quad * 8];
    bf16x8 a1 = *(const bf16x8*)&As[arow * LDK + 32 + quad * 8];
#pragma unroll
    for (int c = 0; c < 4; ++c) {
      bf16x8 b0 = *(const bf16x8*)&Bs[0][(c * 16 + lr) * LDK + quad * 8];
      bf16x8 b1 = *(const bf16x8*)&Bs[0][(c * 16 + lr) * LDK + 32 + quad * 8];
      acc[c] = mfma_bf16(a0, b0, acc[c]);
      acc[c] = mfma_bf16(a1, b1, acc[c]);
    }
    if (!att) {
#pragma unroll
      for (int c = 0; c < 4; ++c) {
        bf16x8 b0 = *(const bf16x8*)&Bs[1][(c * 16 + lr) * LDK + quad * 8];
        bf16x8 b1 = *(const bf16x8*)&Bs[1][(c * 16 + lr) * LDK + 32 + quad * 8];
        acc[4 + c] = mfma_bf16(a0, b0, acc[4 + c]);
        acc[4 + c] = mfma_bf16(a1, b1, acc[4 + c]);
      }
    }
    __syncthreads();
  }
  if (att) {
#pragma unroll
    for (int j = 0; j < 4; ++j) {
      int row = r0 + wave * 16 + quad * 4 + j;
      float v0 = acc[0][j];
      float sum = v0 + __shfl_xor(v0, 4);   // hi + lo partner
      if (lr < 4)                    a_s[(size_t)row * 4 + lr] = sum;
      else if (lr >= 8 && lr < 12)   a_d[(size_t)row * 4 + (lr - 8)] = sum;
    }
    return;
  }
#pragma unroll
  for (int t = 0; t < 2; ++t) {
#pragma unroll
    for (int c = 0; c < 4; ++c) {
#pragma unroll
      for (int j = 0; j < 4; ++j) {
        int row = r0 + wave * 16 + quad * 4 + j;
        int cg = cb + t * 64 + c * 16 + lr;
        ushort v = f2bf(acc[t * 4 + c][j] + bias[cg]);
        if (cg < halfw) out0[(size_t)row * halfw + cg] = v;
        else            out1[(size_t)row * halfw + cg - halfw] = v;
      }
    }
  }
}

// ---------------- fused ONLINE softmax + weighted aggregate + bias + skip (+relu) ----
// Single pass over each node's in-edges: running max m, rescale s/acc on update
// (rare: ~log(deg) times), 2-edge unrolled. VEC=8 lanes (16B uint4 gathers).
// Lane layout: LPH=CH/8 lanes per head, LPN=4*LPH per node, NPW=64/LPN nodes/wave.
__device__ __forceinline__ void load_bf8(const ushort* p, float* o) {
  uint4 q = *(const uint4*)p;
  o[0] = bf2f(q.x & 0xffffu); o[1] = bf2f(q.x >> 16);
  o[2] = bf2f(q.y & 0xffffu); o[3] = bf2f(q.y >> 16);
  o[4] = bf2f(q.z & 0xffffu); o[5] = bf2f(q.z >> 16);
  o[6] = bf2f(q.w & 0xffffu); o[7] = bf2f(q.w >> 16);
}

template <int CH, bool RELU, bool OUT_BF16>
__launch_bounds__(256)
__global__ void gat_fused_kernel(const int* __restrict__ off, const int* __restrict__ srcs,
                                 const float* __restrict__ a_s, const float* __restrict__ a_d,
                                 const ushort* __restrict__ xs,
                                 const float* __restrict__ bias,
                                 const ushort* __restrict__ skip,
                                 void* __restrict__ outv, int N) {
  const int HC  = 4 * CH;
  const int LPH = CH / 8;       // lanes per head
  const int LPN = 4 * LPH;      // lanes per node
  const int NPW = 64 / LPN;     // nodes per wave
  int wave = threadIdx.x >> 6, lane = threadIdx.x & 63;
  int g  = lane / LPN;
  int hl = (lane % LPN) / LPH;
  int li = lane % LPH;
  int n = blockIdx.x * (4 * NPW) + wave * NPW + g;
  if (n >= N) return;
  int i = off[n], end = off[n + 1];
  float adn = a_d[(size_t)n * 4 + hl];
  const int cofs = hl * CH + li * 8;

  float m = -1e30f, s = 0.f;
  float acc[8];
#pragma unroll
  for (int v = 0; v < 8; ++v) acc[v] = 0.f;

  for (; i + 2 <= end; i += 2) {
    int sA = srcs[i], sB = srcs[i + 1];
    float eA = lrelu(a_s[(size_t)sA * 4 + hl] + adn);
    float eB = lrelu(a_s[(size_t)sB * 4 + hl] + adn);
    float xA[8], xB[8];
    load_bf8(xs + (size_t)sA * HC + cofs, xA);
    load_bf8(xs + (size_t)sB * HC + cofs, xB);
    float mn = fmaxf(m, fmaxf(eA, eB));
    if (mn > m) {
      float f = __expf(m - mn);
      s *= f;
#pragma unroll
      for (int v = 0; v < 8; ++v) acc[v] *= f;
      m = mn;
    }
    float pA = __expf(eA - m), pB = __expf(eB - m);
    s += pA + pB;
#pragma unroll
    for (int v = 0; v < 8; ++v) acc[v] += pA * xA[v] + pB * xB[v];
  }
  if (i < end) {
    int sA = srcs[i];
    float eA = lrelu(a_s[(size_t)sA * 4 + hl] + adn);
    float xA[8];
    load_bf8(xs + (size_t)sA * HC + cofs, xA);
    if (eA > m) {
      float f = __expf(m - eA);
      s *= f;
#pragma unroll
      for (int v = 0; v < 8; ++v) acc[v] *= f;
      m = eA;
    }
    float pA = __expf(eA - m);
    s += pA;
#pragma unroll
    for (int v = 0; v < 8; ++v) acc[v] += pA * xA[v];
  }

  float r = s > 0.f ? 1.f / s : 0.f;
  size_t obase = (size_t)n * HC + cofs;
  float sk[8];
  load_bf8(skip + obase, sk);
  float val[8];
#pragma unroll
  for (int v = 0; v < 8; ++v) {
    val[v] = acc[v] * r + bias[cofs + v] + sk[v];
    if (RELU) val[v] = fmaxf(val[v], 0.f);
  }
  if (OUT_BF16) {
    ushort o8[8];
#pragma unroll
    for (int v = 0; v < 8; ++v) o8[v] = f2bf(val[v]);
    *(uint4*)&((ushort*)outv)[obase] = *(const uint4*)o8;
  } else {
    float* op = (float*)outv + obase;
    *(float4*)op = make_float4(val[0], val[1], val[2], val[3]);
    *(float4*)(op + 4) = make_float4(val[4], val[5], val[6], val[7]);
  }
}

// ---------------- host launch ----------------
extern "C" void kernel_launch(void* const* d_in, const int* in_sizes, int n_in,
                              void* d_out, int out_size, void* d_ws, size_t ws_size,
                              hipStream_t stream) {
  const float* x      = (const float*)d_in[0];
  const int*   ei     = (const int*)d_in[1];
  const float* W_rna  = (const float*)d_in[3];
  const float* b_rna  = (const float*)d_in[4];
  const float* W_prot = (const float*)d_in[5];
  const float* b_prot = (const float*)d_in[6];
  const float* W1s    = (const float*)d_in[7];
  const float* W1d    = (const float*)d_in[8];
  const float* at1s   = (const float*)d_in[9];
  const float* at1d   = (const float*)d_in[10];
  const float* bias1  = (const float*)d_in[11];
  const float* Wl1    = (const float*)d_in[12];
  const float* bl1    = (const float*)d_in[13];
  const float* W2s    = (const float*)d_in[14];
  const float* W2d    = (const float*)d_in[15];
  const float* at2s   = (const float*)d_in[16];
  const float* at2d   = (const float*)d_in[17];
  const float* bias2  = (const float*)d_in[18];
  const float* Wl2    = (const float*)d_in[19];
  const float* bl2    = (const float*)d_in[20];

  const int N = in_sizes[0] / D_IN;   // 40000
  const int E = in_sizes[1] / 2;      // 640000
  const int* srcv = ei;
  const int* dstv = ei + E;

  char* ws = (char*)d_ws;
  size_t o = 0;
  auto carve = [&](size_t bytes) {
    void* p = ws + o;
    o += (bytes + 255) & ~(size_t)255;
    return p;
  };
  int* deg    = (int*)carve((size_t)N * 4);
  int* offp   = (int*)carve((size_t)(N + 1) * 4);
  int* cur    = (int*)carve((size_t)N * 4);
  int* srcs   = (int*)carve((size_t)E * 4);
  float* a_s  = (float*)carve((size_t)N * 4 * 4);
  float* a_d  = (float*)carve((size_t)N * 4 * 4);
  ushort* BTr = (ushort*)carve(64 * 1024 * 2);
  ushort* BTp = (ushort*)carve(64 * 384 * 2);
  ushort* BT1 = (ushort*)carve(512 * 128 * 2);
  ushort* BT2 = (ushort*)carve(256 * 256 * 2);
  ushort* BTA1 = (ushort*)carve(64 * 128 * 2);
  ushort* BTA2 = (ushort*)carve(64 * 256 * 2);
  float* biasL1 = (float*)carve(512 * 4);
  float* biasL2 = (float*)carve(256 * 4);
  ushort* h0  = (ushort*)carve((size_t)N * HDIM * 2);
  ushort* xs1 = (ushort*)carve((size_t)N * HC1 * 2);
  ushort* z1  = (ushort*)carve((size_t)N * HC1 * 2);
  ushort* h1  = (ushort*)carve((size_t)N * HC1 * 2);
  ushort* xs2 = h0;   // h0 dead after layer-1 gemm (att folded in)
  ushort* z2  = z1;   // z1 dead after gat_fused1
  float* out = (float*)d_out;

  // 1. counting-sort edges by dst
  zero_i32<<<(N + 255) / 256, 256, 0, stream>>>(deg, N);
  hist_kernel<<<(E + 255) / 256, 256, 0, stream>>>(dstv, deg, E);
  scan_kernel<<<1, 1024, 0, stream>>>(deg, offp, cur, N);
  scatter_kernel<<<(E + 255) / 256, 256, 0, stream>>>(srcv, dstv, cur, srcs, E);
  // 2. fold att (-> BTA tiles) + weight conversion
  fold_att_kernel<<<8, 256, 0, stream>>>(W1s, W1d, at1s, at1d, W2s, W2d, at2s, at2d,
                                         BTA1, BTA2);
  convert_weights<<<256, 256, 0, stream>>>(W_rna, W_prot, W1s, Wl1, W2s, Wl2,
                                           bias1, bl1, bias2, bl2,
                                           BTr, BTp, BT1, BT2, biasL1, biasL2);
  // 3. embedding -> h0[N,128] bf16 (512-thread in-block split-K)
  embed_gemm<<<dim3(2, N / 64), 512, 0, stream>>>(x, BTr, BTp, b_rna, b_prot, h0);
  // 4. layer-1: [xs1|z1] = h0 @ [W1s|Wl1] (+bias) and a_s/a_d (att block), bf16
  layer_gemm<<<dim3(5, N / 64), 256, 0, stream>>>(h0, HDIM, BT1, biasL1, xs1, z1, HC1,
                                                  BTA1, a_s, a_d);
  // 5. fused online softmax+aggregate -> h1 = relu(agg + bias1 + z1), bf16
  gat_fused_kernel<CH1, true, true><<<N / 8, 256, 0, stream>>>(offp, srcs, a_s, a_d, xs1,
                                                               bias1, z1, h1, N);
  // 6. layer-2
  layer_gemm<<<dim3(3, N / 64), 256, 0, stream>>>(h1, HC1, BT2, biasL2, xs2, z2, HC2,
                                                  BTA2, a_s, a_d);
  gat_fused_kernel<CH2, false, false><<<N / 16, 256, 0, stream>>>(offp, srcs, a_s, a_d, xs2,
                                                                  bias2, z2, out, N);
}

// Round 9
// 653.421 us; speedup vs baseline: 1.0392x; 1.0392x over previous
//
#include <hip/hip_runtime.h>
#include <hip/hip_bf16.h>
#include <stdint.h>

// GraRPINet: 2-layer GAT. N=40000 nodes, E=640000 edges.
// R3: all GEMMs -> bf16 MFMA (16x16x32), weights pre-transposed bf16 BT[n][k].
// R4/R6/R7/R11 (reverted): FIVE embed attacks failed (LDS-free, split-K global,
// BM=32, 512-thread in-block split-K). Embed's R5 config (~124us, 256thr, BM=64)
// is a hard local optimum -- FROZEN. Lesson: zero extra DRAM traffic; occupancy
// counter does not respond to bigger blocks (limiter is not LDS/VGPR arithmetic).
// R8 (WIN, 762->707): attn_proj folded into layer_gemm; edge_softmax fused into agg.
// R9 (neutral): layer_gemm col-group G=2. R10 (WIN, 701->655): online-softmax
// single-pass gat_fused + VEC=8 gathers.
// R12: embed restored to R5-exact; gat_fused 4-edge unroll with batched load issue
// (4 srcs -> 4 a_s + 4 xs-rows in flight before compute) to cover gather latency.

#define HEADS 4
#define CH1   64
#define CH2   32
#define HC1   256
#define HC2   128

static constexpr int D_RNA  = 1000;
static constexpr int D_PROT = 300;
static constexpr int D_IN   = 1300;
static constexpr int HDIM   = 128;  // 2H

typedef __bf16 bf16x8 __attribute__((ext_vector_type(8)));
typedef float  f32x4  __attribute__((ext_vector_type(4)));
typedef unsigned short ushort;

__device__ __forceinline__ float lrelu(float x) { return x >= 0.f ? x : 0.2f * x; }
__device__ __forceinline__ float bf2f(unsigned int u16) {
  return __uint_as_float(u16 << 16);
}
__device__ __forceinline__ ushort f2bf(float f) {
  union { float f; unsigned int u; } x; x.f = f;
  unsigned int r = x.u + 0x7fffu + ((x.u >> 16) & 1u);
  return (ushort)(r >> 16);
}

// ---------------- small utility kernels ----------------
__global__ void zero_i32(int* p, int n) {
  int i = blockIdx.x * 256 + threadIdx.x;
  if (i < n) p[i] = 0;
}

__global__ void hist_kernel(const int* __restrict__ dstv, int* __restrict__ deg, int E) {
  int i = blockIdx.x * 256 + threadIdx.x;
  if (i < E) atomicAdd(&deg[dstv[i]], 1);
}

__global__ void scan_kernel(const int* __restrict__ deg, int* __restrict__ off,
                            int* __restrict__ cur, int n) {
  __shared__ int s[1024];
  int tid = threadIdx.x;
  const int CHK = (n + 1023) / 1024;
  int base = tid * CHK;
  int sum = 0;
  for (int j = 0; j < CHK; ++j) {
    int i = base + j;
    if (i < n) sum += deg[i];
  }
  s[tid] = sum;
  __syncthreads();
  for (int o = 1; o < 1024; o <<= 1) {
    int t = (tid >= o) ? s[tid - o] : 0;
    __syncthreads();
    s[tid] += t;
    __syncthreads();
  }
  int run = s[tid] - sum;
  for (int j = 0; j < CHK; ++j) {
    int i = base + j;
    if (i < n) {
      off[i] = run; cur[i] = run;
      run += deg[i];
    }
  }
  if (tid == 1023) off[n] = s[1023];
}

__global__ void scatter_kernel(const int* __restrict__ srcv, const int* __restrict__ dstv,
                               int* __restrict__ cur, int* __restrict__ srcs, int E) {
  int i = blockIdx.x * 256 + threadIdx.x;
  if (i < E) {
    int d = dstv[i];
    int pos = atomicAdd(&cur[d], 1);
    srcs[pos] = srcv[i];
  }
}

// fold att vectors v[k,h] = sum_c W[k, h*CH+c]*att[h,c], then pack as GEMM B-tiles:
// BTA[64][K]: rows 0..3 = vs_hi, 4..7 = vs_lo, 8..11 = vd_hi, 12..15 = vd_lo,
// rows 16..63 = 0. hi/lo bf16 split keeps logits at ~fp32 precision.
__global__ void fold_att_kernel(const float* __restrict__ W1s, const float* __restrict__ W1d,
                                const float* __restrict__ at1s, const float* __restrict__ at1d,
                                const float* __restrict__ W2s, const float* __restrict__ W2d,
                                const float* __restrict__ at2s, const float* __restrict__ at2d,
                                ushort* __restrict__ BTA1, ushort* __restrict__ BTA2) {
  int tid = blockIdx.x * blockDim.x + threadIdx.x;
  int stride = gridDim.x * blockDim.x;
  for (int o = tid; o < HDIM * HEADS; o += stride) {
    int k = o >> 2, h = o & 3;
    float ss = 0.f, sd = 0.f;
    for (int c = 0; c < CH1; ++c) {
      ss += W1s[k * HC1 + h * CH1 + c] * at1s[h * CH1 + c];
      sd += W1d[k * HC1 + h * CH1 + c] * at1d[h * CH1 + c];
    }
    ushort sh = f2bf(ss), dh = f2bf(sd);
    BTA1[(0 + h) * HDIM + k] = sh;
    BTA1[(4 + h) * HDIM + k] = f2bf(ss - bf2f(sh));
    BTA1[(8 + h) * HDIM + k] = dh;
    BTA1[(12 + h) * HDIM + k] = f2bf(sd - bf2f(dh));
  }
  for (int o = tid; o < HC1 * HEADS; o += stride) {
    int k = o >> 2, h = o & 3;
    float ss = 0.f, sd = 0.f;
    for (int c = 0; c < CH2; ++c) {
      ss += W2s[k * HC2 + h * CH2 + c] * at2s[h * CH2 + c];
      sd += W2d[k * HC2 + h * CH2 + c] * at2d[h * CH2 + c];
    }
    ushort sh = f2bf(ss), dh = f2bf(sd);
    BTA2[(0 + h) * HC1 + k] = sh;
    BTA2[(4 + h) * HC1 + k] = f2bf(ss - bf2f(sh));
    BTA2[(8 + h) * HC1 + k] = dh;
    BTA2[(12 + h) * HC1 + k] = f2bf(sd - bf2f(dh));
  }
  for (int i = tid; i < 48 * HDIM; i += stride) BTA1[16 * HDIM + i] = 0;
  for (int i = tid; i < 48 * HC1; i += stride) BTA2[16 * HC1 + i] = 0;
}

// ---------------- weight preprocessing: transpose + bf16 ----------------
// BTr[64][1024] (k>=1000 zero), BTp[64][320] (k>=300 zero),
// BT1[512][128] = [W1s|Wl1]^T, BT2[256][256] = [W2s|Wl2]^T, concat biases.
__global__ void convert_weights(const float* __restrict__ W_rna, const float* __restrict__ W_prot,
                                const float* __restrict__ W1s, const float* __restrict__ Wl1,
                                const float* __restrict__ W2s, const float* __restrict__ Wl2,
                                const float* __restrict__ b1, const float* __restrict__ bl1,
                                const float* __restrict__ b2, const float* __restrict__ bl2,
                                ushort* BTr, ushort* BTp, ushort* BT1, ushort* BT2,
                                float* biasL1, float* biasL2) {
  int tid = blockIdx.x * blockDim.x + threadIdx.x;
  int stride = gridDim.x * blockDim.x;
  for (int i = tid; i < 64 * 1024; i += stride) {
    int n = i >> 10, k = i & 1023;
    BTr[i] = (k < D_RNA) ? f2bf(W_rna[k * 64 + n]) : 0;
  }
  for (int i = tid; i < 64 * 320; i += stride) {
    int n = i / 320, k = i - n * 320;
    BTp[i] = (k < D_PROT) ? f2bf(W_prot[k * 64 + n]) : 0;
  }
  for (int i = tid; i < 512 * 128; i += stride) {
    int n = i >> 7, k = i & 127;
    BT1[i] = f2bf(n < 256 ? W1s[k * 256 + n] : Wl1[k * 256 + n - 256]);
  }
  for (int i = tid; i < 256 * 256; i += stride) {
    int n = i >> 8, k = i & 255;
    BT2[i] = f2bf(n < 128 ? W2s[k * 128 + n] : Wl2[k * 128 + n - 128]);
  }
  for (int i = tid; i < 512; i += stride) biasL1[i] = (i < 256) ? b1[i] : bl1[i - 256];
  for (int i = tid; i < 256; i += stride) biasL2[i] = (i < 128) ? b2[i] : bl2[i - 128];
}

#define LDK 72  // padded k-stride (shorts) for 64-wide k tiles: 144B rows -> 2-way-only conflicts

__device__ __forceinline__ f32x4 mfma_bf16(bf16x8 a, bf16x8 b, f32x4 c) {
  return __builtin_amdgcn_mfma_f32_16x16x32_bf16(a, b, c, 0, 0, 0);
}

// ---------------- embedding MFMA GEMM: h0[N,128] bf16 (R5-exact, FROZEN) ----------
__launch_bounds__(256)
__global__ void embed_gemm(const float* __restrict__ x,
                           const ushort* __restrict__ BTr, const ushort* __restrict__ BTp,
                           const float* __restrict__ b_rna, const float* __restrict__ b_prot,
                           ushort* __restrict__ h0) {
  const bool prot = (blockIdx.x == 1);
  const int Kpad = prot ? 320 : 1024;
  const int acol = prot ? D_RNA : 0;
  const ushort* BT = prot ? BTp : BTr;
  const float* bias = prot ? b_prot : b_rna;
  const int r0 = blockIdx.y * 64;

  __shared__ ushort As[64 * LDK];
  __shared__ ushort Bs[64 * LDK];
  int tid = threadIdx.x;
  int wave = tid >> 6, lane = tid & 63;
  int quad = lane >> 4, lr = lane & 15;
  f32x4 acc[4];
#pragma unroll
  for (int c = 0; c < 4; ++c) acc[c] = (f32x4){0.f, 0.f, 0.f, 0.f};

  int srow = tid >> 2, skq = (tid & 3) * 16;
  const float* aprow = x + (size_t)(r0 + srow) * D_IN;
  const ushort* bprow = BT + (size_t)srow * Kpad;

  float4 fa[4];
  uint4 fb0, fb1;

  auto loadA = [&](int k0) {
#pragma unroll
    for (int q = 0; q < 4; ++q) {
      int kg = acol + k0 + skq + q * 4;
      fa[q] = (kg + 4 <= D_IN) ? *(const float4*)(aprow + kg)
                               : make_float4(0.f, 0.f, 0.f, 0.f);
    }
  };
  auto loadB = [&](int k0) {
    const ushort* bp = bprow + k0 + skq;
    fb0 = *(const uint4*)bp;
    fb1 = *(const uint4*)(bp + 8);
  };

  loadA(0);
  loadB(0);

  for (int k0 = 0; k0 < Kpad; k0 += 64) {
    {
      ushort tmp[16];
#pragma unroll
      for (int q = 0; q < 4; ++q) {
        tmp[q * 4 + 0] = f2bf(fa[q].x); tmp[q * 4 + 1] = f2bf(fa[q].y);
        tmp[q * 4 + 2] = f2bf(fa[q].z); tmp[q * 4 + 3] = f2bf(fa[q].w);
      }
      *(uint4*)&As[srow * LDK + skq] = *(const uint4*)&tmp[0];
      *(uint4*)&As[srow * LDK + skq + 8] = *(const uint4*)&tmp[8];
      *(uint4*)&Bs[srow * LDK + skq] = fb0;
      *(uint4*)&Bs[srow * LDK + skq + 8] = fb1;
    }
    __syncthreads();
    if (k0 + 64 < Kpad) {
      loadA(k0 + 64);
      loadB(k0 + 64);
    }
    int arow = wave * 16 + lr;
    bf16x8 a0 = *(const bf16x8*)&As[arow * LDK + quad * 8];
    bf16x8 a1 = *(const bf16x8*)&As[arow * LDK + 32 + quad * 8];
#pragma unroll
    for (int c = 0; c < 4; ++c) {
      bf16x8 b0 = *(const bf16x8*)&Bs[(c * 16 + lr) * LDK + quad * 8];
      bf16x8 b1 = *(const bf16x8*)&Bs[(c * 16 + lr) * LDK + 32 + quad * 8];
      acc[c] = mfma_bf16(a0, b0, acc[c]);
      acc[c] = mfma_bf16(a1, b1, acc[c]);
    }
    __syncthreads();
  }
  int colb = prot ? 64 : 0;
#pragma unroll
  for (int c = 0; c < 4; ++c) {
#pragma unroll
    for (int j = 0; j < 4; ++j) {
      int row = r0 + wave * 16 + quad * 4 + j;
      int col = c * 16 + lr;
      h0[(size_t)row * HDIM + colb + col] = f2bf(acc[c][j] + bias[col]);
    }
  }
}

// ---------------- layer MFMA GEMM (col-group G=2) + folded attention logits ----------
// grid (ngroups+1, N/64). Regular block x: cols [x*128, x*128+128) = 2 B-tiles sharing
// one staged A-tile. Last x-block uses BTA (single tile) and writes fp32 a_s/a_d:
// out col t(0..3) hi + col t+4 lo summed via shfl_xor(4) -> a_s; cols 8..15 -> a_d.
__launch_bounds__(256)
__global__ void layer_gemm(const ushort* __restrict__ A, int K,
                           const ushort* __restrict__ BT, const float* __restrict__ bias,
                           ushort* __restrict__ out0, ushort* __restrict__ out1, int halfw,
                           const ushort* __restrict__ BTA,
                           float* __restrict__ a_s, float* __restrict__ a_d) {
  const bool att = (blockIdx.x == gridDim.x - 1);
  const int cb = att ? 0 : blockIdx.x * 128;
  const int r0 = blockIdx.y * 64;
  __shared__ ushort As[64 * LDK];
  __shared__ ushort Bs[2][64 * LDK];
  int tid = threadIdx.x;
  int wave = tid >> 6, lane = tid & 63;
  int quad = lane >> 4, lr = lane & 15;
  f32x4 acc[8];
#pragma unroll
  for (int c = 0; c < 8; ++c) acc[c] = (f32x4){0.f, 0.f, 0.f, 0.f};

  int srow = tid >> 2, skq = (tid & 3) * 16;
  const ushort* aprow = A + (size_t)(r0 + srow) * K;
  const ushort* bprow0 = att ? (BTA + (size_t)srow * K)
                             : (BT + (size_t)(cb + srow) * K);
  const ushort* bprow1 = BT + (size_t)(cb + 64 + srow) * K;   // unused when att

  uint4 fa0, fa1, fb00, fb01, fb10, fb11;
  auto loadAB = [&](int k0) {
    const ushort* ap = aprow + k0 + skq;
    fa0 = *(const uint4*)ap;
    fa1 = *(const uint4*)(ap + 8);
    const ushort* bp0 = bprow0 + k0 + skq;
    fb00 = *(const uint4*)bp0;
    fb01 = *(const uint4*)(bp0 + 8);
    if (!att) {
      const ushort* bp1 = bprow1 + k0 + skq;
      fb10 = *(const uint4*)bp1;
      fb11 = *(const uint4*)(bp1 + 8);
    }
  };

  loadAB(0);

  for (int k0 = 0; k0 < K; k0 += 64) {
    *(uint4*)&As[srow * LDK + skq] = fa0;
    *(uint4*)&As[srow * LDK + skq + 8] = fa1;
    *(uint4*)&Bs[0][srow * LDK + skq] = fb00;
    *(uint4*)&Bs[0][srow * LDK + skq + 8] = fb01;
    if (!att) {
      *(uint4*)&Bs[1][srow * LDK + skq] = fb10;
      *(uint4*)&Bs[1][srow * LDK + skq + 8] = fb11;
    }
    __syncthreads();
    if (k0 + 64 < K) loadAB(k0 + 64);
    int arow = wave * 16 + lr;
    bf16x8 a0 = *(const bf16x8*)&As[arow * LDK + quad * 8];
    bf16x8 a1 = *(const bf16x8*)&As[arow * LDK + 32 + quad * 8];
#pragma unroll
    for (int c = 0; c < 4; ++c) {
      bf16x8 b0 = *(const bf16x8*)&Bs[0][(c * 16 + lr) * LDK + quad * 8];
      bf16x8 b1 = *(const bf16x8*)&Bs[0][(c * 16 + lr) * LDK + 32 + quad * 8];
      acc[c] = mfma_bf16(a0, b0, acc[c]);
      acc[c] = mfma_bf16(a1, b1, acc[c]);
    }
    if (!att) {
#pragma unroll
      for (int c = 0; c < 4; ++c) {
        bf16x8 b0 = *(const bf16x8*)&Bs[1][(c * 16 + lr) * LDK + quad * 8];
        bf16x8 b1 = *(const bf16x8*)&Bs[1][(c * 16 + lr) * LDK + 32 + quad * 8];
        acc[4 + c] = mfma_bf16(a0, b0, acc[4 + c]);
        acc[4 + c] = mfma_bf16(a1, b1, acc[4 + c]);
      }
    }
    __syncthreads();
  }
  if (att) {
#pragma unroll
    for (int j = 0; j < 4; ++j) {
      int row = r0 + wave * 16 + quad * 4 + j;
      float v0 = acc[0][j];
      float sum = v0 + __shfl_xor(v0, 4);   // hi + lo partner
      if (lr < 4)                    a_s[(size_t)row * 4 + lr] = sum;
      else if (lr >= 8 && lr < 12)   a_d[(size_t)row * 4 + (lr - 8)] = sum;
    }
    return;
  }
#pragma unroll
  for (int t = 0; t < 2; ++t) {
#pragma unroll
    for (int c = 0; c < 4; ++c) {
#pragma unroll
      for (int j = 0; j < 4; ++j) {
        int row = r0 + wave * 16 + quad * 4 + j;
        int cg = cb + t * 64 + c * 16 + lr;
        ushort v = f2bf(acc[t * 4 + c][j] + bias[cg]);
        if (cg < halfw) out0[(size_t)row * halfw + cg] = v;
        else            out1[(size_t)row * halfw + cg - halfw] = v;
      }
    }
  }
}

// ---------------- fused ONLINE softmax + weighted aggregate + bias + skip (+relu) ----
// Single pass, 4-edge unroll with BATCHED load issue: 4 srcs -> 4 a_s + 4 xs rows all
// in flight before first use (covers scattered-load latency). One max-update per batch.
// VEC=8 lanes (16B uint4 gathers). LPH=CH/8 lanes/head, NPW=64/(4*LPH) nodes/wave.
__device__ __forceinline__ void load_bf8(const ushort* p, float* o) {
  uint4 q = *(const uint4*)p;
  o[0] = bf2f(q.x & 0xffffu); o[1] = bf2f(q.x >> 16);
  o[2] = bf2f(q.y & 0xffffu); o[3] = bf2f(q.y >> 16);
  o[4] = bf2f(q.z & 0xffffu); o[5] = bf2f(q.z >> 16);
  o[6] = bf2f(q.w & 0xffffu); o[7] = bf2f(q.w >> 16);
}

template <int CH, bool RELU, bool OUT_BF16>
__launch_bounds__(256)
__global__ void gat_fused_kernel(const int* __restrict__ off, const int* __restrict__ srcs,
                                 const float* __restrict__ a_s, const float* __restrict__ a_d,
                                 const ushort* __restrict__ xs,
                                 const float* __restrict__ bias,
                                 const ushort* __restrict__ skip,
                                 void* __restrict__ outv, int N) {
  const int HC  = 4 * CH;
  const int LPH = CH / 8;       // lanes per head
  const int LPN = 4 * LPH;      // lanes per node
  const int NPW = 64 / LPN;     // nodes per wave
  int wave = threadIdx.x >> 6, lane = threadIdx.x & 63;
  int g  = lane / LPN;
  int hl = (lane % LPN) / LPH;
  int li = lane % LPH;
  int n = blockIdx.x * (4 * NPW) + wave * NPW + g;
  if (n >= N) return;
  int i = off[n], end = off[n + 1];
  float adn = a_d[(size_t)n * 4 + hl];
  const int cofs = hl * CH + li * 8;

  float m = -1e30f, s = 0.f;
  float acc[8];
#pragma unroll
  for (int v = 0; v < 8; ++v) acc[v] = 0.f;

  for (; i + 4 <= end; i += 4) {
    int s0 = srcs[i], s1 = srcs[i + 1], s2 = srcs[i + 2], s3 = srcs[i + 3];
    // issue all 8 gathers before any use
    float e0 = a_s[(size_t)s0 * 4 + hl];
    float e1 = a_s[(size_t)s1 * 4 + hl];
    float e2 = a_s[(size_t)s2 * 4 + hl];
    float e3 = a_s[(size_t)s3 * 4 + hl];
    float x0[8], x1[8], x2[8], x3[8];
    load_bf8(xs + (size_t)s0 * HC + cofs, x0);
    load_bf8(xs + (size_t)s1 * HC + cofs, x1);
    load_bf8(xs + (size_t)s2 * HC + cofs, x2);
    load_bf8(xs + (size_t)s3 * HC + cofs, x3);
    e0 = lrelu(e0 + adn); e1 = lrelu(e1 + adn);
    e2 = lrelu(e2 + adn); e3 = lrelu(e3 + adn);
    float em = fmaxf(fmaxf(e0, e1), fmaxf(e2, e3));
    if (em > m) {
      float f = __expf(m - em);
      s *= f;
#pragma unroll
      for (int v = 0; v < 8; ++v) acc[v] *= f;
      m = em;
    }
    float p0 = __expf(e0 - m), p1 = __expf(e1 - m);
    float p2 = __expf(e2 - m), p3 = __expf(e3 - m);
    s += (p0 + p1) + (p2 + p3);
#pragma unroll
    for (int v = 0; v < 8; ++v)
      acc[v] += (p0 * x0[v] + p1 * x1[v]) + (p2 * x2[v] + p3 * x3[v]);
  }
  for (; i < end; ++i) {
    int sA = srcs[i];
    float eA = lrelu(a_s[(size_t)sA * 4 + hl] + adn);
    float xA[8];
    load_bf8(xs + (size_t)sA * HC + cofs, xA);
    if (eA > m) {
      float f = __expf(m - eA);
      s *= f;
#pragma unroll
      for (int v = 0; v < 8; ++v) acc[v] *= f;
      m = eA;
    }
    float pA = __expf(eA - m);
    s += pA;
#pragma unroll
    for (int v = 0; v < 8; ++v) acc[v] += pA * xA[v];
  }

  float r = s > 0.f ? 1.f / s : 0.f;
  size_t obase = (size_t)n * HC + cofs;
  float sk[8];
  load_bf8(skip + obase, sk);
  float val[8];
#pragma unroll
  for (int v = 0; v < 8; ++v) {
    val[v] = acc[v] * r + bias[cofs + v] + sk[v];
    if (RELU) val[v] = fmaxf(val[v], 0.f);
  }
  if (OUT_BF16) {
    ushort o8[8];
#pragma unroll
    for (int v = 0; v < 8; ++v) o8[v] = f2bf(val[v]);
    *(uint4*)&((ushort*)outv)[obase] = *(const uint4*)o8;
  } else {
    float* op = (float*)outv + obase;
    *(float4*)op = make_float4(val[0], val[1], val[2], val[3]);
    *(float4*)(op + 4) = make_float4(val[4], val[5], val[6], val[7]);
  }
}

// ---------------- host launch ----------------
extern "C" void kernel_launch(void* const* d_in, const int* in_sizes, int n_in,
                              void* d_out, int out_size, void* d_ws, size_t ws_size,
                              hipStream_t stream) {
  const float* x      = (const float*)d_in[0];
  const int*   ei     = (const int*)d_in[1];
  const float* W_rna  = (const float*)d_in[3];
  const float* b_rna  = (const float*)d_in[4];
  const float* W_prot = (const float*)d_in[5];
  const float* b_prot = (const float*)d_in[6];
  const float* W1s    = (const float*)d_in[7];
  const float* W1d    = (const float*)d_in[8];
  const float* at1s   = (const float*)d_in[9];
  const float* at1d   = (const float*)d_in[10];
  const float* bias1  = (const float*)d_in[11];
  const float* Wl1    = (const float*)d_in[12];
  const float* bl1    = (const float*)d_in[13];
  const float* W2s    = (const float*)d_in[14];
  const float* W2d    = (const float*)d_in[15];
  const float* at2s   = (const float*)d_in[16];
  const float* at2d   = (const float*)d_in[17];
  const float* bias2  = (const float*)d_in[18];
  const float* Wl2    = (const float*)d_in[19];
  const float* bl2    = (const float*)d_in[20];

  const int N = in_sizes[0] / D_IN;   // 40000
  const int E = in_sizes[1] / 2;      // 640000
  const int* srcv = ei;
  const int* dstv = ei + E;

  char* ws = (char*)d_ws;
  size_t o = 0;
  auto carve = [&](size_t bytes) {
    void* p = ws + o;
    o += (bytes + 255) & ~(size_t)255;
    return p;
  };
  int* deg    = (int*)carve((size_t)N * 4);
  int* offp   = (int*)carve((size_t)(N + 1) * 4);
  int* cur    = (int*)carve((size_t)N * 4);
  int* srcs   = (int*)carve((size_t)E * 4);
  float* a_s  = (float*)carve((size_t)N * 4 * 4);
  float* a_d  = (float*)carve((size_t)N * 4 * 4);
  ushort* BTr = (ushort*)carve(64 * 1024 * 2);
  ushort* BTp = (ushort*)carve(64 * 320 * 2);
  ushort* BT1 = (ushort*)carve(512 * 128 * 2);
  ushort* BT2 = (ushort*)carve(256 * 256 * 2);
  ushort* BTA1 = (ushort*)carve(64 * 128 * 2);
  ushort* BTA2 = (ushort*)carve(64 * 256 * 2);
  float* biasL1 = (float*)carve(512 * 4);
  float* biasL2 = (float*)carve(256 * 4);
  ushort* h0  = (ushort*)carve((size_t)N * HDIM * 2);
  ushort* xs1 = (ushort*)carve((size_t)N * HC1 * 2);
  ushort* z1  = (ushort*)carve((size_t)N * HC1 * 2);
  ushort* h1  = (ushort*)carve((size_t)N * HC1 * 2);
  ushort* xs2 = h0;   // h0 dead after layer-1 gemm (att folded in)
  ushort* z2  = z1;   // z1 dead after gat_fused1
  float* out = (float*)d_out;

  // 1. counting-sort edges by dst
  zero_i32<<<(N + 255) / 256, 256, 0, stream>>>(deg, N);
  hist_kernel<<<(E + 255) / 256, 256, 0, stream>>>(dstv, deg, E);
  scan_kernel<<<1, 1024, 0, stream>>>(deg, offp, cur, N);
  scatter_kernel<<<(E + 255) / 256, 256, 0, stream>>>(srcv, dstv, cur, srcs, E);
  // 2. fold att (-> BTA tiles) + weight conversion
  fold_att_kernel<<<8, 256, 0, stream>>>(W1s, W1d, at1s, at1d, W2s, W2d, at2s, at2d,
                                         BTA1, BTA2);
  convert_weights<<<256, 256, 0, stream>>>(W_rna, W_prot, W1s, Wl1, W2s, Wl2,
                                           bias1, bl1, bias2, bl2,
                                           BTr, BTp, BT1, BT2, biasL1, biasL2);
  // 3. embedding -> h0[N,128] bf16
  embed_gemm<<<dim3(2, N / 64), 256, 0, stream>>>(x, BTr, BTp, b_rna, b_prot, h0);
  // 4. layer-1: [xs1|z1] = h0 @ [W1s|Wl1] (+bias) and a_s/a_d (att block), bf16
  layer_gemm<<<dim3(5, N / 64), 256, 0, stream>>>(h0, HDIM, BT1, biasL1, xs1, z1, HC1,
                                                  BTA1, a_s, a_d);
  // 5. fused online softmax+aggregate -> h1 = relu(agg + bias1 + z1), bf16
  gat_fused_kernel<CH1, true, true><<<N / 8, 256, 0, stream>>>(offp, srcs, a_s, a_d, xs1,
                                                               bias1, z1, h1, N);
  // 6. layer-2
  layer_gemm<<<dim3(3, N / 64), 256, 0, stream>>>(h1, HC1, BT2, biasL2, xs2, z2, HC2,
                                                  BTA2, a_s, a_d);
  gat_fused_kernel<CH2, false, false><<<N / 16, 256, 0, stream>>>(offp, srcs, a_s, a_d, xs2,
                                                                  bias2, z2, out, N);
}

// Round 10
// 653.343 us; speedup vs baseline: 1.0393x; 1.0001x over previous
//
#include <hip/hip_runtime.h>
#include <hip/hip_bf16.h>
#include <stdint.h>

// GraRPINet: 2-layer GAT. N=40000 nodes, E=640000 edges.
// R3: all GEMMs -> bf16 MFMA (16x16x32), weights pre-transposed bf16 BT[n][k].
// R4/R6/R7/R11 (reverted): FIVE embed attacks failed. Embed's R5 config (~124us)
// FROZEN -- limiter is strided-read DRAM efficiency, not occupancy/LDS/VGPR.
// R8 (WIN, 762->707): attn_proj folded into layer_gemm; edge_softmax fused into agg.
// R9 (neutral): layer_gemm col-group G=2. R10 (WIN, 701->655): online-softmax
// single-pass gat_fused + VEC=8. R12 (null on gat): 4-edge batching -- chain LENGTH,
// not MLP, is the gat bottleneck (R10: removing a 13MB-gather pass saved 46us =>
// latency-bound serial edge walk).
// R13: gat ESPLIT=2 -- each node's edge list split across two lane-group halves
// (even/odd edges), online-softmax states merged via shfl_xor at the end. Halves
// the per-node serial gather depth (deg~16 -> 8) + better degree-imbalance.

#define HEADS 4
#define CH1   64
#define CH2   32
#define HC1   256
#define HC2   128

static constexpr int D_RNA  = 1000;
static constexpr int D_PROT = 300;
static constexpr int D_IN   = 1300;
static constexpr int HDIM   = 128;  // 2H

typedef __bf16 bf16x8 __attribute__((ext_vector_type(8)));
typedef float  f32x4  __attribute__((ext_vector_type(4)));
typedef unsigned short ushort;

__device__ __forceinline__ float lrelu(float x) { return x >= 0.f ? x : 0.2f * x; }
__device__ __forceinline__ float bf2f(unsigned int u16) {
  return __uint_as_float(u16 << 16);
}
__device__ __forceinline__ ushort f2bf(float f) {
  union { float f; unsigned int u; } x; x.f = f;
  unsigned int r = x.u + 0x7fffu + ((x.u >> 16) & 1u);
  return (ushort)(r >> 16);
}

// ---------------- small utility kernels ----------------
__global__ void zero_i32(int* p, int n) {
  int i = blockIdx.x * 256 + threadIdx.x;
  if (i < n) p[i] = 0;
}

__global__ void hist_kernel(const int* __restrict__ dstv, int* __restrict__ deg, int E) {
  int i = blockIdx.x * 256 + threadIdx.x;
  if (i < E) atomicAdd(&deg[dstv[i]], 1);
}

__global__ void scan_kernel(const int* __restrict__ deg, int* __restrict__ off,
                            int* __restrict__ cur, int n) {
  __shared__ int s[1024];
  int tid = threadIdx.x;
  const int CHK = (n + 1023) / 1024;
  int base = tid * CHK;
  int sum = 0;
  for (int j = 0; j < CHK; ++j) {
    int i = base + j;
    if (i < n) sum += deg[i];
  }
  s[tid] = sum;
  __syncthreads();
  for (int o = 1; o < 1024; o <<= 1) {
    int t = (tid >= o) ? s[tid - o] : 0;
    __syncthreads();
    s[tid] += t;
    __syncthreads();
  }
  int run = s[tid] - sum;
  for (int j = 0; j < CHK; ++j) {
    int i = base + j;
    if (i < n) {
      off[i] = run; cur[i] = run;
      run += deg[i];
    }
  }
  if (tid == 1023) off[n] = s[1023];
}

__global__ void scatter_kernel(const int* __restrict__ srcv, const int* __restrict__ dstv,
                               int* __restrict__ cur, int* __restrict__ srcs, int E) {
  int i = blockIdx.x * 256 + threadIdx.x;
  if (i < E) {
    int d = dstv[i];
    int pos = atomicAdd(&cur[d], 1);
    srcs[pos] = srcv[i];
  }
}

// fold att vectors v[k,h] = sum_c W[k, h*CH+c]*att[h,c], then pack as GEMM B-tiles:
// BTA[64][K]: rows 0..3 = vs_hi, 4..7 = vs_lo, 8..11 = vd_hi, 12..15 = vd_lo,
// rows 16..63 = 0. hi/lo bf16 split keeps logits at ~fp32 precision.
__global__ void fold_att_kernel(const float* __restrict__ W1s, const float* __restrict__ W1d,
                                const float* __restrict__ at1s, const float* __restrict__ at1d,
                                const float* __restrict__ W2s, const float* __restrict__ W2d,
                                const float* __restrict__ at2s, const float* __restrict__ at2d,
                                ushort* __restrict__ BTA1, ushort* __restrict__ BTA2) {
  int tid = blockIdx.x * blockDim.x + threadIdx.x;
  int stride = gridDim.x * blockDim.x;
  for (int o = tid; o < HDIM * HEADS; o += stride) {
    int k = o >> 2, h = o & 3;
    float ss = 0.f, sd = 0.f;
    for (int c = 0; c < CH1; ++c) {
      ss += W1s[k * HC1 + h * CH1 + c] * at1s[h * CH1 + c];
      sd += W1d[k * HC1 + h * CH1 + c] * at1d[h * CH1 + c];
    }
    ushort sh = f2bf(ss), dh = f2bf(sd);
    BTA1[(0 + h) * HDIM + k] = sh;
    BTA1[(4 + h) * HDIM + k] = f2bf(ss - bf2f(sh));
    BTA1[(8 + h) * HDIM + k] = dh;
    BTA1[(12 + h) * HDIM + k] = f2bf(sd - bf2f(dh));
  }
  for (int o = tid; o < HC1 * HEADS; o += stride) {
    int k = o >> 2, h = o & 3;
    float ss = 0.f, sd = 0.f;
    for (int c = 0; c < CH2; ++c) {
      ss += W2s[k * HC2 + h * CH2 + c] * at2s[h * CH2 + c];
      sd += W2d[k * HC2 + h * CH2 + c] * at2d[h * CH2 + c];
    }
    ushort sh = f2bf(ss), dh = f2bf(sd);
    BTA2[(0 + h) * HC1 + k] = sh;
    BTA2[(4 + h) * HC1 + k] = f2bf(ss - bf2f(sh));
    BTA2[(8 + h) * HC1 + k] = dh;
    BTA2[(12 + h) * HC1 + k] = f2bf(sd - bf2f(dh));
  }
  for (int i = tid; i < 48 * HDIM; i += stride) BTA1[16 * HDIM + i] = 0;
  for (int i = tid; i < 48 * HC1; i += stride) BTA2[16 * HC1 + i] = 0;
}

// ---------------- weight preprocessing: transpose + bf16 ----------------
// BTr[64][1024] (k>=1000 zero), BTp[64][320] (k>=300 zero),
// BT1[512][128] = [W1s|Wl1]^T, BT2[256][256] = [W2s|Wl2]^T, concat biases.
__global__ void convert_weights(const float* __restrict__ W_rna, const float* __restrict__ W_prot,
                                const float* __restrict__ W1s, const float* __restrict__ Wl1,
                                const float* __restrict__ W2s, const float* __restrict__ Wl2,
                                const float* __restrict__ b1, const float* __restrict__ bl1,
                                const float* __restrict__ b2, const float* __restrict__ bl2,
                                ushort* BTr, ushort* BTp, ushort* BT1, ushort* BT2,
                                float* biasL1, float* biasL2) {
  int tid = blockIdx.x * blockDim.x + threadIdx.x;
  int stride = gridDim.x * blockDim.x;
  for (int i = tid; i < 64 * 1024; i += stride) {
    int n = i >> 10, k = i & 1023;
    BTr[i] = (k < D_RNA) ? f2bf(W_rna[k * 64 + n]) : 0;
  }
  for (int i = tid; i < 64 * 320; i += stride) {
    int n = i / 320, k = i - n * 320;
    BTp[i] = (k < D_PROT) ? f2bf(W_prot[k * 64 + n]) : 0;
  }
  for (int i = tid; i < 512 * 128; i += stride) {
    int n = i >> 7, k = i & 127;
    BT1[i] = f2bf(n < 256 ? W1s[k * 256 + n] : Wl1[k * 256 + n - 256]);
  }
  for (int i = tid; i < 256 * 256; i += stride) {
    int n = i >> 8, k = i & 255;
    BT2[i] = f2bf(n < 128 ? W2s[k * 128 + n] : Wl2[k * 128 + n - 128]);
  }
  for (int i = tid; i < 512; i += stride) biasL1[i] = (i < 256) ? b1[i] : bl1[i - 256];
  for (int i = tid; i < 256; i += stride) biasL2[i] = (i < 128) ? b2[i] : bl2[i - 128];
}

#define LDK 72  // padded k-stride (shorts) for 64-wide k tiles: 144B rows -> 2-way-only conflicts

__device__ __forceinline__ f32x4 mfma_bf16(bf16x8 a, bf16x8 b, f32x4 c) {
  return __builtin_amdgcn_mfma_f32_16x16x32_bf16(a, b, c, 0, 0, 0);
}

// ---------------- embedding MFMA GEMM: h0[N,128] bf16 (R5-exact, FROZEN) ----------
__launch_bounds__(256)
__global__ void embed_gemm(const float* __restrict__ x,
                           const ushort* __restrict__ BTr, const ushort* __restrict__ BTp,
                           const float* __restrict__ b_rna, const float* __restrict__ b_prot,
                           ushort* __restrict__ h0) {
  const bool prot = (blockIdx.x == 1);
  const int Kpad = prot ? 320 : 1024;
  const int acol = prot ? D_RNA : 0;
  const ushort* BT = prot ? BTp : BTr;
  const float* bias = prot ? b_prot : b_rna;
  const int r0 = blockIdx.y * 64;

  __shared__ ushort As[64 * LDK];
  __shared__ ushort Bs[64 * LDK];
  int tid = threadIdx.x;
  int wave = tid >> 6, lane = tid & 63;
  int quad = lane >> 4, lr = lane & 15;
  f32x4 acc[4];
#pragma unroll
  for (int c = 0; c < 4; ++c) acc[c] = (f32x4){0.f, 0.f, 0.f, 0.f};

  int srow = tid >> 2, skq = (tid & 3) * 16;
  const float* aprow = x + (size_t)(r0 + srow) * D_IN;
  const ushort* bprow = BT + (size_t)srow * Kpad;

  float4 fa[4];
  uint4 fb0, fb1;

  auto loadA = [&](int k0) {
#pragma unroll
    for (int q = 0; q < 4; ++q) {
      int kg = acol + k0 + skq + q * 4;
      fa[q] = (kg + 4 <= D_IN) ? *(const float4*)(aprow + kg)
                               : make_float4(0.f, 0.f, 0.f, 0.f);
    }
  };
  auto loadB = [&](int k0) {
    const ushort* bp = bprow + k0 + skq;
    fb0 = *(const uint4*)bp;
    fb1 = *(const uint4*)(bp + 8);
  };

  loadA(0);
  loadB(0);

  for (int k0 = 0; k0 < Kpad; k0 += 64) {
    {
      ushort tmp[16];
#pragma unroll
      for (int q = 0; q < 4; ++q) {
        tmp[q * 4 + 0] = f2bf(fa[q].x); tmp[q * 4 + 1] = f2bf(fa[q].y);
        tmp[q * 4 + 2] = f2bf(fa[q].z); tmp[q * 4 + 3] = f2bf(fa[q].w);
      }
      *(uint4*)&As[srow * LDK + skq] = *(const uint4*)&tmp[0];
      *(uint4*)&As[srow * LDK + skq + 8] = *(const uint4*)&tmp[8];
      *(uint4*)&Bs[srow * LDK + skq] = fb0;
      *(uint4*)&Bs[srow * LDK + skq + 8] = fb1;
    }
    __syncthreads();
    if (k0 + 64 < Kpad) {
      loadA(k0 + 64);
      loadB(k0 + 64);
    }
    int arow = wave * 16 + lr;
    bf16x8 a0 = *(const bf16x8*)&As[arow * LDK + quad * 8];
    bf16x8 a1 = *(const bf16x8*)&As[arow * LDK + 32 + quad * 8];
#pragma unroll
    for (int c = 0; c < 4; ++c) {
      bf16x8 b0 = *(const bf16x8*)&Bs[(c * 16 + lr) * LDK + quad * 8];
      bf16x8 b1 = *(const bf16x8*)&Bs[(c * 16 + lr) * LDK + 32 + quad * 8];
      acc[c] = mfma_bf16(a0, b0, acc[c]);
      acc[c] = mfma_bf16(a1, b1, acc[c]);
    }
    __syncthreads();
  }
  int colb = prot ? 64 : 0;
#pragma unroll
  for (int c = 0; c < 4; ++c) {
#pragma unroll
    for (int j = 0; j < 4; ++j) {
      int row = r0 + wave * 16 + quad * 4 + j;
      int col = c * 16 + lr;
      h0[(size_t)row * HDIM + colb + col] = f2bf(acc[c][j] + bias[col]);
    }
  }
}

// ---------------- layer MFMA GEMM (col-group G=2) + folded attention logits ----------
// grid (ngroups+1, N/64). Regular block x: cols [x*128, x*128+128) = 2 B-tiles sharing
// one staged A-tile. Last x-block uses BTA (single tile) and writes fp32 a_s/a_d:
// out col t(0..3) hi + col t+4 lo summed via shfl_xor(4) -> a_s; cols 8..15 -> a_d.
__launch_bounds__(256)
__global__ void layer_gemm(const ushort* __restrict__ A, int K,
                           const ushort* __restrict__ BT, const float* __restrict__ bias,
                           ushort* __restrict__ out0, ushort* __restrict__ out1, int halfw,
                           const ushort* __restrict__ BTA,
                           float* __restrict__ a_s, float* __restrict__ a_d) {
  const bool att = (blockIdx.x == gridDim.x - 1);
  const int cb = att ? 0 : blockIdx.x * 128;
  const int r0 = blockIdx.y * 64;
  __shared__ ushort As[64 * LDK];
  __shared__ ushort Bs[2][64 * LDK];
  int tid = threadIdx.x;
  int wave = tid >> 6, lane = tid & 63;
  int quad = lane >> 4, lr = lane & 15;
  f32x4 acc[8];
#pragma unroll
  for (int c = 0; c < 8; ++c) acc[c] = (f32x4){0.f, 0.f, 0.f, 0.f};

  int srow = tid >> 2, skq = (tid & 3) * 16;
  const ushort* aprow = A + (size_t)(r0 + srow) * K;
  const ushort* bprow0 = att ? (BTA + (size_t)srow * K)
                             : (BT + (size_t)(cb + srow) * K);
  const ushort* bprow1 = BT + (size_t)(cb + 64 + srow) * K;   // unused when att

  uint4 fa0, fa1, fb00, fb01, fb10, fb11;
  auto loadAB = [&](int k0) {
    const ushort* ap = aprow + k0 + skq;
    fa0 = *(const uint4*)ap;
    fa1 = *(const uint4*)(ap + 8);
    const ushort* bp0 = bprow0 + k0 + skq;
    fb00 = *(const uint4*)bp0;
    fb01 = *(const uint4*)(bp0 + 8);
    if (!att) {
      const ushort* bp1 = bprow1 + k0 + skq;
      fb10 = *(const uint4*)bp1;
      fb11 = *(const uint4*)(bp1 + 8);
    }
  };

  loadAB(0);

  for (int k0 = 0; k0 < K; k0 += 64) {
    *(uint4*)&As[srow * LDK + skq] = fa0;
    *(uint4*)&As[srow * LDK + skq + 8] = fa1;
    *(uint4*)&Bs[0][srow * LDK + skq] = fb00;
    *(uint4*)&Bs[0][srow * LDK + skq + 8] = fb01;
    if (!att) {
      *(uint4*)&Bs[1][srow * LDK + skq] = fb10;
      *(uint4*)&Bs[1][srow * LDK + skq + 8] = fb11;
    }
    __syncthreads();
    if (k0 + 64 < K) loadAB(k0 + 64);
    int arow = wave * 16 + lr;
    bf16x8 a0 = *(const bf16x8*)&As[arow * LDK + quad * 8];
    bf16x8 a1 = *(const bf16x8*)&As[arow * LDK + 32 + quad * 8];
#pragma unroll
    for (int c = 0; c < 4; ++c) {
      bf16x8 b0 = *(const bf16x8*)&Bs[0][(c * 16 + lr) * LDK + quad * 8];
      bf16x8 b1 = *(const bf16x8*)&Bs[0][(c * 16 + lr) * LDK + 32 + quad * 8];
      acc[c] = mfma_bf16(a0, b0, acc[c]);
      acc[c] = mfma_bf16(a1, b1, acc[c]);
    }
    if (!att) {
#pragma unroll
      for (int c = 0; c < 4; ++c) {
        bf16x8 b0 = *(const bf16x8*)&Bs[1][(c * 16 + lr) * LDK + quad * 8];
        bf16x8 b1 = *(const bf16x8*)&Bs[1][(c * 16 + lr) * LDK + 32 + quad * 8];
        acc[4 + c] = mfma_bf16(a0, b0, acc[4 + c]);
        acc[4 + c] = mfma_bf16(a1, b1, acc[4 + c]);
      }
    }
    __syncthreads();
  }
  if (att) {
#pragma unroll
    for (int j = 0; j < 4; ++j) {
      int row = r0 + wave * 16 + quad * 4 + j;
      float v0 = acc[0][j];
      float sum = v0 + __shfl_xor(v0, 4);   // hi + lo partner
      if (lr < 4)                    a_s[(size_t)row * 4 + lr] = sum;
      else if (lr >= 8 && lr < 12)   a_d[(size_t)row * 4 + (lr - 8)] = sum;
    }
    return;
  }
#pragma unroll
  for (int t = 0; t < 2; ++t) {
#pragma unroll
    for (int c = 0; c < 4; ++c) {
#pragma unroll
      for (int j = 0; j < 4; ++j) {
        int row = r0 + wave * 16 + quad * 4 + j;
        int cg = cb + t * 64 + c * 16 + lr;
        ushort v = f2bf(acc[t * 4 + c][j] + bias[cg]);
        if (cg < halfw) out0[(size_t)row * halfw + cg] = v;
        else            out1[(size_t)row * halfw + cg - halfw] = v;
      }
    }
  }
}

// ---------------- fused ONLINE softmax + aggregate, ESPLIT=2 ----------------
// Each node's edge list split across two lane-group halves (even/odd edges); each
// half runs the online-softmax walk on deg/2 edges; states merged via shfl_xor(CLN)
// (partner lane holds the same channels of the other half):
//   m' = max(mA,mB); f = e^(m-m'); s = s*f + partner(s*f); acc likewise.
// Halves the serial dependent-gather depth per node (R10 showed this walk is
// latency-bound). VEC=8 lanes (16B uint4 gathers); epilogue gated to half 0.
__device__ __forceinline__ void load_bf8(const ushort* p, float* o) {
  uint4 q = *(const uint4*)p;
  o[0] = bf2f(q.x & 0xffffu); o[1] = bf2f(q.x >> 16);
  o[2] = bf2f(q.y & 0xffffu); o[3] = bf2f(q.y >> 16);
  o[4] = bf2f(q.z & 0xffffu); o[5] = bf2f(q.z >> 16);
  o[6] = bf2f(q.w & 0xffffu); o[7] = bf2f(q.w >> 16);
}

template <int CH, bool RELU, bool OUT_BF16>
__launch_bounds__(256)
__global__ void gat_fused_kernel(const int* __restrict__ off, const int* __restrict__ srcs,
                                 const float* __restrict__ a_s, const float* __restrict__ a_d,
                                 const ushort* __restrict__ xs,
                                 const float* __restrict__ bias,
                                 const ushort* __restrict__ skip,
                                 void* __restrict__ outv, int N) {
  const int HC  = 4 * CH;
  const int LPH = CH / 8;       // channel-lanes per head
  const int CLN = 4 * LPH;      // channel-lanes per node (32 L1, 16 L2)
  const int LPN = 2 * CLN;      // lanes per node incl. edge-split (64 L1, 32 L2)
  const int NPW = 64 / LPN;     // nodes per wave (1 L1, 2 L2)
  int wave = threadIdx.x >> 6, lane = threadIdx.x & 63;
  int g   = lane / LPN;
  int rem = lane % LPN;
  int es  = rem / CLN;          // edge-split half (0/1); partner = lane ^ CLN
  int cl  = rem % CLN;
  int hl  = cl / LPH;
  int li  = cl % LPH;
  int n = blockIdx.x * (4 * NPW) + wave * NPW + g;
  if (n >= N) return;
  int s0 = off[n], end = off[n + 1];
  float adn = a_d[(size_t)n * 4 + hl];
  const int cofs = hl * CH + li * 8;

  float m = -1e30f, s = 0.f;
  float acc[8];
#pragma unroll
  for (int v = 0; v < 8; ++v) acc[v] = 0.f;

  // this half walks edges s0+es, s0+es+2, ... ; 2-edge batch (stride 2 within half)
  int i = s0 + es;
  for (; i + 2 < end; i += 4) {
    int sA = srcs[i], sB = srcs[i + 2];
    float eA = a_s[(size_t)sA * 4 + hl];
    float eB = a_s[(size_t)sB * 4 + hl];
    float xA[8], xB[8];
    load_bf8(xs + (size_t)sA * HC + cofs, xA);
    load_bf8(xs + (size_t)sB * HC + cofs, xB);
    eA = lrelu(eA + adn); eB = lrelu(eB + adn);
    float em = fmaxf(eA, eB);
    if (em > m) {
      float f = __expf(m - em);
      s *= f;
#pragma unroll
      for (int v = 0; v < 8; ++v) acc[v] *= f;
      m = em;
    }
    float pA = __expf(eA - m), pB = __expf(eB - m);
    s += pA + pB;
#pragma unroll
    for (int v = 0; v < 8; ++v) acc[v] += pA * xA[v] + pB * xB[v];
  }
  for (; i < end; i += 2) {
    int sA = srcs[i];
    float eA = lrelu(a_s[(size_t)sA * 4 + hl] + adn);
    float xA[8];
    load_bf8(xs + (size_t)sA * HC + cofs, xA);
    if (eA > m) {
      float f = __expf(m - eA);
      s *= f;
#pragma unroll
      for (int v = 0; v < 8; ++v) acc[v] *= f;
      m = eA;
    }
    float pA = __expf(eA - m);
    s += pA;
#pragma unroll
    for (int v = 0; v < 8; ++v) acc[v] += pA * xA[v];
  }

  // merge the two halves (partner lane = lane ^ CLN, same channels)
  {
    float m2 = fmaxf(m, __shfl_xor(m, CLN));
    float f = __expf(m - m2);        // 0 if this half empty (m = -1e30)
    s *= f;
    s += __shfl_xor(s, CLN);
#pragma unroll
    for (int v = 0; v < 8; ++v) {
      acc[v] *= f;
      acc[v] += __shfl_xor(acc[v], CLN);
    }
  }
  if (es != 0) return;

  float r = s > 0.f ? 1.f / s : 0.f;
  size_t obase = (size_t)n * HC + cofs;
  float sk[8];
  load_bf8(skip + obase, sk);
  float val[8];
#pragma unroll
  for (int v = 0; v < 8; ++v) {
    val[v] = acc[v] * r + bias[cofs + v] + sk[v];
    if (RELU) val[v] = fmaxf(val[v], 0.f);
  }
  if (OUT_BF16) {
    ushort o8[8];
#pragma unroll
    for (int v = 0; v < 8; ++v) o8[v] = f2bf(val[v]);
    *(uint4*)&((ushort*)outv)[obase] = *(const uint4*)o8;
  } else {
    float* op = (float*)outv + obase;
    *(float4*)op = make_float4(val[0], val[1], val[2], val[3]);
    *(float4*)(op + 4) = make_float4(val[4], val[5], val[6], val[7]);
  }
}

// ---------------- host launch ----------------
extern "C" void kernel_launch(void* const* d_in, const int* in_sizes, int n_in,
                              void* d_out, int out_size, void* d_ws, size_t ws_size,
                              hipStream_t stream) {
  const float* x      = (const float*)d_in[0];
  const int*   ei     = (const int*)d_in[1];
  const float* W_rna  = (const float*)d_in[3];
  const float* b_rna  = (const float*)d_in[4];
  const float* W_prot = (const float*)d_in[5];
  const float* b_prot = (const float*)d_in[6];
  const float* W1s    = (const float*)d_in[7];
  const float* W1d    = (const float*)d_in[8];
  const float* at1s   = (const float*)d_in[9];
  const float* at1d   = (const float*)d_in[10];
  const float* bias1  = (const float*)d_in[11];
  const float* Wl1    = (const float*)d_in[12];
  const float* bl1    = (const float*)d_in[13];
  const float* W2s    = (const float*)d_in[14];
  const float* W2d    = (const float*)d_in[15];
  const float* at2s   = (const float*)d_in[16];
  const float* at2d   = (const float*)d_in[17];
  const float* bias2  = (const float*)d_in[18];
  const float* Wl2    = (const float*)d_in[19];
  const float* bl2    = (const float*)d_in[20];

  const int N = in_sizes[0] / D_IN;   // 40000
  const int E = in_sizes[1] / 2;      // 640000
  const int* srcv = ei;
  const int* dstv = ei + E;

  char* ws = (char*)d_ws;
  size_t o = 0;
  auto carve = [&](size_t bytes) {
    void* p = ws + o;
    o += (bytes + 255) & ~(size_t)255;
    return p;
  };
  int* deg    = (int*)carve((size_t)N * 4);
  int* offp   = (int*)carve((size_t)(N + 1) * 4);
  int* cur    = (int*)carve((size_t)N * 4);
  int* srcs   = (int*)carve((size_t)E * 4);
  float* a_s  = (float*)carve((size_t)N * 4 * 4);
  float* a_d  = (float*)carve((size_t)N * 4 * 4);
  ushort* BTr = (ushort*)carve(64 * 1024 * 2);
  ushort* BTp = (ushort*)carve(64 * 320 * 2);
  ushort* BT1 = (ushort*)carve(512 * 128 * 2);
  ushort* BT2 = (ushort*)carve(256 * 256 * 2);
  ushort* BTA1 = (ushort*)carve(64 * 128 * 2);
  ushort* BTA2 = (ushort*)carve(64 * 256 * 2);
  float* biasL1 = (float*)carve(512 * 4);
  float* biasL2 = (float*)carve(256 * 4);
  ushort* h0  = (ushort*)carve((size_t)N * HDIM * 2);
  ushort* xs1 = (ushort*)carve((size_t)N * HC1 * 2);
  ushort* z1  = (ushort*)carve((size_t)N * HC1 * 2);
  ushort* h1  = (ushort*)carve((size_t)N * HC1 * 2);
  ushort* xs2 = h0;   // h0 dead after layer-1 gemm (att folded in)
  ushort* z2  = z1;   // z1 dead after gat_fused1
  float* out = (float*)d_out;

  // 1. counting-sort edges by dst
  zero_i32<<<(N + 255) / 256, 256, 0, stream>>>(deg, N);
  hist_kernel<<<(E + 255) / 256, 256, 0, stream>>>(dstv, deg, E);
  scan_kernel<<<1, 1024, 0, stream>>>(deg, offp, cur, N);
  scatter_kernel<<<(E + 255) / 256, 256, 0, stream>>>(srcv, dstv, cur, srcs, E);
  // 2. fold att (-> BTA tiles) + weight conversion
  fold_att_kernel<<<8, 256, 0, stream>>>(W1s, W1d, at1s, at1d, W2s, W2d, at2s, at2d,
                                         BTA1, BTA2);
  convert_weights<<<256, 256, 0, stream>>>(W_rna, W_prot, W1s, Wl1, W2s, Wl2,
                                           bias1, bl1, bias2, bl2,
                                           BTr, BTp, BT1, BT2, biasL1, biasL2);
  // 3. embedding -> h0[N,128] bf16
  embed_gemm<<<dim3(2, N / 64), 256, 0, stream>>>(x, BTr, BTp, b_rna, b_prot, h0);
  // 4. layer-1: [xs1|z1] = h0 @ [W1s|Wl1] (+bias) and a_s/a_d (att block), bf16
  layer_gemm<<<dim3(5, N / 64), 256, 0, stream>>>(h0, HDIM, BT1, biasL1, xs1, z1, HC1,
                                                  BTA1, a_s, a_d);
  // 5. fused online softmax+aggregate (ESPLIT=2) -> h1, bf16
  gat_fused_kernel<CH1, true, true><<<N / 4, 256, 0, stream>>>(offp, srcs, a_s, a_d, xs1,
                                                               bias1, z1, h1, N);
  // 6. layer-2
  layer_gemm<<<dim3(3, N / 64), 256, 0, stream>>>(h1, HC1, BT2, biasL2, xs2, z2, HC2,
                                                  BTA2, a_s, a_d);
  gat_fused_kernel<CH2, false, false><<<N / 8, 256, 0, stream>>>(offp, srcs, a_s, a_d, xs2,
                                                                 bias2, z2, out, N);
}